// Round 8
// baseline (740.666 us; speedup 1.0000x reference)
//
#include <hip/hip_runtime.h>

// ---------------------------------------------------------------------------
// LennardJones per-atom energy — bucketed two-pass.
//
// R20: discriminating experiment for the constant ~414us of wall-minus-passA
// (stable across 3 different back-ends: R13/R14 partial+reduce, R19 direct
// 245-block). H1: it's fixed harness reset/launch overhead (my models say
// passB ~50us). H2: both passB forms coincidentally cost ~350us.
//  * passA byte-identical to R19 (323us, counters as measured).
//  * passB -> nb*8=1960 blocks x 256thr (R14's proven slice shape), LDS
//    partial e[2048] per (bucket,slice), then coalesced global atomicAdd
//    into energy. No partial buffer, no reduce kernel. Energy pre-zeroed.
// Predicted: passA unchanged; wall ~500 => H2 (passB real, keep going);
// wall ~730 => H1 (414 is harness-fixed; passA is the only target left).
// ws-guarded; fallbacks: R7 packed float4, then R1.
// ---------------------------------------------------------------------------

#define BUCKET_SHIFT 11
#define BUCKET_SIZE  2048
#define SLICES       8
#define QSCALE       2048.0f
#define QINV         (1.0f / 2048.0f)

#define A_THREADS 512
#define A_PAIRS   8

typedef int vint4 __attribute__((ext_vector_type(4)));

__global__ void lj_zero_kernel(float* __restrict__ out, long n) {
    long i = (long)blockIdx.x * blockDim.x + threadIdx.x;
    if (i < n) out[i] = 0.0f;
}

// tab8[a] = x_u16 | y_u16<<16 | z_u16<<32 | species<<48  (coords * 2048)
// Also initializes cursor[b] = b * cap (folded to save a dispatch).
__global__ void lj_pack8_kernel(const float* __restrict__ pos,
                                const int* __restrict__ species,
                                unsigned long long* __restrict__ tab8,
                                int* __restrict__ cursor,
                                int nb, int cap, int n) {
    int i = blockIdx.x * blockDim.x + threadIdx.x;
    if (i < n) {
        unsigned int ux = (unsigned int)(pos[3 * i]     * QSCALE + 0.5f) & 0xFFFFu;
        unsigned int uy = (unsigned int)(pos[3 * i + 1] * QSCALE + 0.5f) & 0xFFFFu;
        unsigned int uz = (unsigned int)(pos[3 * i + 2] * QSCALE + 0.5f) & 0xFFFFu;
        unsigned long long w = (unsigned long long)ux
                             | ((unsigned long long)uy << 16)
                             | ((unsigned long long)uz << 32)
                             | ((unsigned long long)(species[i] & 3) << 48);
        tab8[i] = w;
    }
    if (i < nb) cursor[i] = i * cap;
}

// float4 pack (fallback path)
__global__ void lj_pack_kernel(const float* __restrict__ pos,
                               const int* __restrict__ species,
                               float4* __restrict__ packed, int n) {
    int i = blockIdx.x * blockDim.x + threadIdx.x;
    if (i < n) {
        float4 p;
        p.x = pos[3 * i];
        p.y = pos[3 * i + 1];
        p.z = pos[3 * i + 2];
        p.w = __int_as_float(species[i]);
        packed[i] = p;
    }
}

// Encode: round he's f32 bits to 12 mantissa bits, pack local id in low 11.
__device__ __forceinline__ unsigned int lj_encode(float he) {
    unsigned int u = __float_as_uint(he);
    return (u + 0x400u) & 0xFFFFF800u;
}

__global__ __launch_bounds__(A_THREADS) void lj_passA_kernel(
    const unsigned long long* __restrict__ tab8,
    const float* __restrict__ cell,
    const float* __restrict__ sigma_tab,
    const float* __restrict__ eps_tab,
    const float* __restrict__ shift_tab,
    const int* __restrict__ pair_i,
    const int* __restrict__ pair_j,
    const int* __restrict__ shifts,
    unsigned int* __restrict__ record_buf,
    int* __restrict__ cursor,
    int cap, int nb, int P)
{
    __shared__ float s_sig6[16];
    __shared__ float s_eps4[16];
    __shared__ float s_shift[16];
    __shared__ float s_cell[9];
    __shared__ int hist[256];
    __shared__ int basev[256];   // global (per-bucket) reservation start
    __shared__ int bbase[256];   // block-local exclusive prefix of hist
    __shared__ unsigned int staged[A_THREADS * A_PAIRS * 2];    // bucket-sorted records
    __shared__ unsigned char bucketOf[A_THREADS * A_PAIRS * 2]; // bucket id per slot
    int t = threadIdx.x;
    if (t < 16) {
        float s = sigma_tab[t];
        float s3 = s * s * s;
        s_sig6[t] = s3 * s3;
        s_eps4[t] = 4.0f * eps_tab[t];
        s_shift[t] = shift_tab[t];
    }
    if (t < 9) s_cell[t] = cell[t];
    if (t < 256) hist[t] = 0;
    __syncthreads();

    float c00 = s_cell[0], c01 = s_cell[1], c02 = s_cell[2];
    float c10 = s_cell[3], c11 = s_cell[4], c12 = s_cell[5];
    float c20 = s_cell[6], c21 = s_cell[7], c22 = s_cell[8];

    long base = (long)(blockIdx.x * (long)A_THREADS + t) * A_PAIRS;

    unsigned int encI[A_PAIRS], encJ[A_PAIRS];  // full records (he | local id)
    int slotij[A_PAIRS];                        // sloti | slotj<<16
    int bkt[A_PAIRS];                           // bi | bj<<8
    int vmask = 0;                              // per-pair validity bits

    if (base + (A_PAIRS - 1) < P) {
        vmask = (1 << A_PAIRS) - 1;
        vint4 piA = *(const vint4*)(pair_i + base);
        vint4 piB = *(const vint4*)(pair_i + base + 4);
        vint4 pjA = *(const vint4*)(pair_j + base);
        vint4 pjB = *(const vint4*)(pair_j + base + 4);
        int pis[A_PAIRS] = {piA[0], piA[1], piA[2], piA[3], piB[0], piB[1], piB[2], piB[3]};
        int pjs[A_PAIRS] = {pjA[0], pjA[1], pjA[2], pjA[3], pjB[0], pjB[1], pjB[2], pjB[3]};

        // issue all 16 gathers before any consumption
        unsigned long long gi[A_PAIRS], gj[A_PAIRS];
#pragma unroll
        for (int k = 0; k < A_PAIRS; ++k) {
            gi[k] = tab8[pis[k]];
            gj[k] = tab8[pjs[k]];
        }

        vint4 s0 = *(const vint4*)(shifts + base * 3);
        vint4 s1 = *(const vint4*)(shifts + base * 3 + 4);
        vint4 s2 = *(const vint4*)(shifts + base * 3 + 8);
        vint4 s3 = *(const vint4*)(shifts + base * 3 + 12);
        vint4 s4 = *(const vint4*)(shifts + base * 3 + 16);
        vint4 s5 = *(const vint4*)(shifts + base * 3 + 20);
        int shv[24] = {s0[0], s0[1], s0[2], s0[3], s1[0], s1[1], s1[2], s1[3],
                       s2[0], s2[1], s2[2], s2[3], s3[0], s3[1], s3[2], s3[3],
                       s4[0], s4[1], s4[2], s4[3], s5[0], s5[1], s5[2], s5[3]};

#pragma unroll
        for (int k = 0; k < A_PAIRS; ++k) {
            float fx = (float)shv[3 * k], fy = (float)shv[3 * k + 1], fz = (float)shv[3 * k + 2];
            unsigned long long wi = gi[k], wj = gj[k];
            int xi = (int)(wi & 0xFFFFu), yi = (int)((wi >> 16) & 0xFFFFu), zi = (int)((wi >> 32) & 0xFFFFu);
            int xj = (int)(wj & 0xFFFFu), yj = (int)((wj >> 16) & 0xFFFFu), zj = (int)((wj >> 32) & 0xFFFFu);
            float dlx = (float)(xj - xi) * QINV;
            float dly = (float)(yj - yi) * QINV;
            float dlz = (float)(zj - zi) * QINV;
            float dx = dlx + fx * c00 + fy * c10 + fz * c20;
            float dy = dly + fx * c01 + fy * c11 + fz * c21;
            float dz = dlz + fx * c02 + fy * c12 + fz * c22;
            float r2 = dx * dx + dy * dy + dz * dz;
            float r6 = r2 * r2 * r2;
            int idx = (int)(wi >> 48) * 4 + (int)(wj >> 48);
            float sr6 = s_sig6[idx] / r6;
            float sr12 = sr6 * sr6;
            float he = 0.5f * (s_eps4[idx] * (sr12 - sr6) - s_shift[idx]);
            unsigned int u = lj_encode(he);
            encI[k] = u | (unsigned int)(pis[k] & (BUCKET_SIZE - 1));
            encJ[k] = u | (unsigned int)(pjs[k] & (BUCKET_SIZE - 1));
            bkt[k] = (pis[k] >> BUCKET_SHIFT) | ((pjs[k] >> BUCKET_SHIFT) << 8);
        }
    } else {
#pragma unroll
        for (int k = 0; k < A_PAIRS; ++k) {
            long p = base + k;
            encI[k] = 0; encJ[k] = 0; bkt[k] = 0;
            if (p < P) {
                vmask |= (1 << k);
                int i = pair_i[p], j = pair_j[p];
                float fx = (float)shifts[3 * p], fy = (float)shifts[3 * p + 1], fz = (float)shifts[3 * p + 2];
                unsigned long long wi = tab8[i];
                unsigned long long wj = tab8[j];
                int xi = (int)(wi & 0xFFFFu), yi = (int)((wi >> 16) & 0xFFFFu), zi = (int)((wi >> 32) & 0xFFFFu);
                int xj = (int)(wj & 0xFFFFu), yj = (int)((wj >> 16) & 0xFFFFu), zj = (int)((wj >> 32) & 0xFFFFu);
                float dlx = (float)(xj - xi) * QINV;
                float dly = (float)(yj - yi) * QINV;
                float dlz = (float)(zj - zi) * QINV;
                float dx = dlx + fx * c00 + fy * c10 + fz * c20;
                float dy = dly + fx * c01 + fy * c11 + fz * c21;
                float dz = dlz + fx * c02 + fy * c12 + fz * c22;
                float r2 = dx * dx + dy * dy + dz * dz;
                float r6 = r2 * r2 * r2;
                int idx = (int)(wi >> 48) * 4 + (int)(wj >> 48);
                float sr6 = s_sig6[idx] / r6;
                float sr12 = sr6 * sr6;
                float he = 0.5f * (s_eps4[idx] * (sr12 - sr6) - s_shift[idx]);
                unsigned int u = lj_encode(he);
                encI[k] = u | (unsigned int)(i & (BUCKET_SIZE - 1));
                encJ[k] = u | (unsigned int)(j & (BUCKET_SIZE - 1));
                bkt[k] = (i >> BUCKET_SHIFT) | ((j >> BUCKET_SHIFT) << 8);
            }
        }
    }

    // Histogram phase (LDS atomics) — slot = rank within (block, bucket).
#pragma unroll
    for (int k = 0; k < A_PAIRS; ++k) {
        if (vmask & (1 << k)) {
            int si = atomicAdd(&hist[bkt[k] & 255], 1);
            int sj = atomicAdd(&hist[(bkt[k] >> 8) & 255], 1);
            slotij[k] = si | (sj << 16);
        } else {
            slotij[k] = 0;
        }
    }
    __syncthreads();

    // Wave 0: exclusive scan of hist -> bbase (block-local bucket offsets).
    if (t < 64) {
        int b0 = t * 4;
        int h0 = hist[b0], h1 = hist[b0 + 1], h2 = hist[b0 + 2], h3 = hist[b0 + 3];
        int s = h0 + h1 + h2 + h3;
        int incl = s;
#pragma unroll
        for (int d = 1; d < 64; d <<= 1) {
            int v = __shfl_up(incl, d, 64);
            if (t >= d) incl += v;
        }
        int excl = incl - s;
        bbase[b0]     = excl;
        bbase[b0 + 1] = excl + h0;
        bbase[b0 + 2] = excl + h0 + h1;
        bbase[b0 + 3] = excl + h0 + h1 + h2;
    }
    // Reserve per-bucket space: ONE global atomic per touched bucket per block.
    if (t < nb) {
        int h = hist[t];
        basev[t] = (h > 0) ? atomicAdd(&cursor[t], h) : 0;
    }
    __syncthreads();

    // Stage records into LDS, bucket-sorted.
#pragma unroll
    for (int k = 0; k < A_PAIRS; ++k) {
        if (vmask & (1 << k)) {
            int bi = bkt[k] & 255;
            int li = bbase[bi] + (slotij[k] & 0xFFFF);
            staged[li] = encI[k];
            bucketOf[li] = (unsigned char)bi;
            int bj = (bkt[k] >> 8) & 255;
            int lj = bbase[bj] + (slotij[k] >> 16);
            staged[lj] = encJ[k];
            bucketOf[lj] = (unsigned char)bj;
        }
    }
    __syncthreads();

    // Coalesced flush: sorted LDS order == contiguous global order per run.
    int total = bbase[255] + hist[255];
    for (int idx = t; idx < total; idx += A_THREADS) {
        int b = (int)bucketOf[idx];
        int g = basev[b] + (idx - bbase[b]);
        if (g < (b + 1) * cap) record_buf[g] = staged[idx];
    }
}

// R20: one block per (bucket, slice) — nb*8 blocks, 256 threads. Accumulate
// the slice's records into an LDS partial, then coalesced global atomicAdd
// into energy (pre-zeroed). No partial buffer, no reduce kernel.
__global__ __launch_bounds__(256) void lj_passB_atomic_kernel(
    const unsigned int* __restrict__ record_buf,
    const int* __restrict__ cursor,
    float* __restrict__ energy,
    int cap, int N)
{
    __shared__ float e[BUCKET_SIZE];
    int blk = blockIdx.x;
    int b = blk >> 3;            // bucket
    int s = blk & (SLICES - 1);  // slice
    int t = threadIdx.x;
#pragma unroll
    for (int k = 0; k < 8; ++k) e[t + 256 * k] = 0.0f;
    __syncthreads();

    int begin = b * cap;
    int count = cursor[b] - begin;
    if (count > cap) count = cap;

    int ngroups = (count + 7) >> 3;
    int gps = (ngroups + SLICES - 1) / SLICES;
    int g0 = s * gps;
    int g1 = g0 + gps;
    if (g1 > ngroups) g1 = ngroups;

    for (int g = g0 + t; g < g1; g += 256) {
        int r0 = g * 8;
        const unsigned int* rp = record_buf + begin + r0;
        if (r0 + 8 <= count) {
            vint4 a = *(const vint4*)(rp);
            vint4 c = *(const vint4*)(rp + 4);
            unsigned int w0 = (unsigned int)a[0], w1 = (unsigned int)a[1];
            unsigned int w2 = (unsigned int)a[2], w3 = (unsigned int)a[3];
            unsigned int w4 = (unsigned int)c[0], w5 = (unsigned int)c[1];
            unsigned int w6 = (unsigned int)c[2], w7 = (unsigned int)c[3];
            atomicAdd(&e[w0 & 2047u], __uint_as_float(w0 & 0xFFFFF800u));
            atomicAdd(&e[w1 & 2047u], __uint_as_float(w1 & 0xFFFFF800u));
            atomicAdd(&e[w2 & 2047u], __uint_as_float(w2 & 0xFFFFF800u));
            atomicAdd(&e[w3 & 2047u], __uint_as_float(w3 & 0xFFFFF800u));
            atomicAdd(&e[w4 & 2047u], __uint_as_float(w4 & 0xFFFFF800u));
            atomicAdd(&e[w5 & 2047u], __uint_as_float(w5 & 0xFFFFF800u));
            atomicAdd(&e[w6 & 2047u], __uint_as_float(w6 & 0xFFFFF800u));
            atomicAdd(&e[w7 & 2047u], __uint_as_float(w7 & 0xFFFFF800u));
        } else {
            for (int r = r0; r < count; ++r) {
                unsigned int w = record_buf[begin + r];
                atomicAdd(&e[w & 2047u], __uint_as_float(w & 0xFFFFF800u));
            }
        }
    }
    __syncthreads();

    // Coalesced global-atomic merge: contiguous addresses per wave.
    long basei = (long)b * BUCKET_SIZE;
#pragma unroll
    for (int k = 0; k < 8; ++k) {
        long i = basei + t + 256 * k;
        float v = e[t + 256 * k];
        if (i < N && v != 0.0f) atomicAdd(&energy[i], v);
    }
}

// ------------------- R7 packed fallback (proven, 1561 us) -------------------
__device__ __forceinline__ void lj_one_pair_packed(
    int i, int j, float fx, float fy, float fz,
    const float4* __restrict__ packed,
    const float* s_sig6, const float* s_eps4, const float* s_shift,
    float c00, float c01, float c02,
    float c10, float c11, float c12,
    float c20, float c21, float c22,
    float* __restrict__ energy)
{
    float4 gi = packed[i];
    float4 gj = packed[j];
    float dx = gj.x - gi.x + fx * c00 + fy * c10 + fz * c20;
    float dy = gj.y - gi.y + fx * c01 + fy * c11 + fz * c21;
    float dz = gj.z - gi.z + fx * c02 + fy * c12 + fz * c22;
    float r2 = dx * dx + dy * dy + dz * dz;
    float r6 = r2 * r2 * r2;
    int idx = __float_as_int(gi.w) * 4 + __float_as_int(gj.w);
    float sr6 = s_sig6[idx] / r6;
    float sr12 = sr6 * sr6;
    float he = 0.5f * (s_eps4[idx] * (sr12 - sr6) - s_shift[idx]);
    atomicAdd(energy + i, he);
    atomicAdd(energy + j, he);
}

__global__ __launch_bounds__(256) void lj_pairs_packed_kernel(
    const float4* __restrict__ packed,
    const float* __restrict__ cell,
    const float* __restrict__ sigma_tab,
    const float* __restrict__ eps_tab,
    const float* __restrict__ shift_tab,
    const int* __restrict__ pair_i,
    const int* __restrict__ pair_j,
    const int* __restrict__ shifts,
    float* __restrict__ energy,
    int P)
{
    __shared__ float s_sig6[16];
    __shared__ float s_eps4[16];
    __shared__ float s_shift[16];
    __shared__ float s_cell[9];
    int t = threadIdx.x;
    if (t < 16) {
        float s = sigma_tab[t];
        float s3 = s * s * s;
        s_sig6[t] = s3 * s3;
        s_eps4[t] = 4.0f * eps_tab[t];
        s_shift[t] = shift_tab[t];
    }
    if (t < 9) s_cell[t] = cell[t];
    __syncthreads();

    float c00 = s_cell[0], c01 = s_cell[1], c02 = s_cell[2];
    float c10 = s_cell[3], c11 = s_cell[4], c12 = s_cell[5];
    float c20 = s_cell[6], c21 = s_cell[7], c22 = s_cell[8];

    long base = (long)(blockIdx.x * (long)blockDim.x + t) * 4;
    if (base + 3 < P) {
        int4 pi4 = *(const int4*)(pair_i + base);
        int4 pj4 = *(const int4*)(pair_j + base);
        int4 sA = *(const int4*)(shifts + base * 3);
        int4 sB = *(const int4*)(shifts + base * 3 + 4);
        int4 sC = *(const int4*)(shifts + base * 3 + 8);
        int pis[4] = {pi4.x, pi4.y, pi4.z, pi4.w};
        int pjs[4] = {pj4.x, pj4.y, pj4.z, pj4.w};
        int shv[12] = {sA.x, sA.y, sA.z, sA.w, sB.x, sB.y, sB.z, sB.w,
                       sC.x, sC.y, sC.z, sC.w};
#pragma unroll
        for (int k = 0; k < 4; ++k) {
            lj_one_pair_packed(pis[k], pjs[k],
                        (float)shv[3 * k], (float)shv[3 * k + 1], (float)shv[3 * k + 2],
                        packed, s_sig6, s_eps4, s_shift,
                        c00, c01, c02, c10, c11, c12, c20, c21, c22, energy);
        }
    } else {
        for (long p = base; p < P; ++p) {
            lj_one_pair_packed(pair_i[p], pair_j[p],
                        (float)shifts[3 * p], (float)shifts[3 * p + 1], (float)shifts[3 * p + 2],
                        packed, s_sig6, s_eps4, s_shift,
                        c00, c01, c02, c10, c11, c12, c20, c21, c22, energy);
        }
    }
}

// --------------------- R1 fallback (no workspace at all) --------------------
__device__ __forceinline__ void lj_one_pair(
    int i, int j, float fx, float fy, float fz,
    const float* __restrict__ pos,
    const int* __restrict__ species,
    const float* s_sig6, const float* s_eps4, const float* s_shift,
    float c00, float c01, float c02,
    float c10, float c11, float c12,
    float c20, float c21, float c22,
    float* __restrict__ energy)
{
    float dx = pos[3 * j]     - pos[3 * i]     + fx * c00 + fy * c10 + fz * c20;
    float dy = pos[3 * j + 1] - pos[3 * i + 1] + fx * c01 + fy * c11 + fz * c21;
    float dz = pos[3 * j + 2] - pos[3 * i + 2] + fx * c02 + fy * c12 + fz * c22;
    float r2 = dx * dx + dy * dy + dz * dz;
    float r6 = r2 * r2 * r2;
    int idx = species[i] * 4 + species[j];
    float sr6 = s_sig6[idx] / r6;
    float sr12 = sr6 * sr6;
    float he = 0.5f * (s_eps4[idx] * (sr12 - sr6) - s_shift[idx]);
    atomicAdd(energy + i, he);
    atomicAdd(energy + j, he);
}

__global__ __launch_bounds__(256) void lj_pairs_kernel(
    const float* __restrict__ pos,
    const float* __restrict__ cell,
    const float* __restrict__ sigma_tab,
    const float* __restrict__ eps_tab,
    const float* __restrict__ shift_tab,
    const int* __restrict__ species,
    const int* __restrict__ pair_i,
    const int* __restrict__ pair_j,
    const int* __restrict__ shifts,
    float* __restrict__ energy,
    int P)
{
    __shared__ float s_sig6[16];
    __shared__ float s_eps4[16];
    __shared__ float s_shift[16];
    __shared__ float s_cell[9];
    int t = threadIdx.x;
    if (t < 16) {
        float s = sigma_tab[t];
        float s3 = s * s * s;
        s_sig6[t] = s3 * s3;
        s_eps4[t] = 4.0f * eps_tab[t];
        s_shift[t] = shift_tab[t];
    }
    if (t < 9) s_cell[t] = cell[t];
    __syncthreads();

    float c00 = s_cell[0], c01 = s_cell[1], c02 = s_cell[2];
    float c10 = s_cell[3], c11 = s_cell[4], c12 = s_cell[5];
    float c20 = s_cell[6], c21 = s_cell[7], c22 = s_cell[8];

    long base = (long)(blockIdx.x * (long)blockDim.x + t) * 4;
    if (base + 3 < P) {
        int4 pi4 = *(const int4*)(pair_i + base);
        int4 pj4 = *(const int4*)(pair_j + base);
        int4 sA = *(const int4*)(shifts + base * 3);
        int4 sB = *(const int4*)(shifts + base * 3 + 4);
        int4 sC = *(const int4*)(shifts + base * 3 + 8);
        int pis[4] = {pi4.x, pi4.y, pi4.z, pi4.w};
        int pjs[4] = {pj4.x, pj4.y, pj4.z, pj4.w};
        int shv[12] = {sA.x, sA.y, sA.z, sA.w, sB.x, sB.y, sB.z, sB.w,
                       sC.x, sC.y, sC.z, sC.w};
#pragma unroll
        for (int k = 0; k < 4; ++k) {
            lj_one_pair(pis[k], pjs[k],
                        (float)shv[3 * k], (float)shv[3 * k + 1], (float)shv[3 * k + 2],
                        pos, species, s_sig6, s_eps4, s_shift,
                        c00, c01, c02, c10, c11, c12, c20, c21, c22, energy);
        }
    } else {
        for (long p = base; p < P; ++p) {
            lj_one_pair(pair_i[p], pair_j[p],
                        (float)shifts[3 * p], (float)shifts[3 * p + 1], (float)shifts[3 * p + 2],
                        pos, species, s_sig6, s_eps4, s_shift,
                        c00, c01, c02, c10, c11, c12, c20, c21, c22, energy);
        }
    }
}

extern "C" void kernel_launch(void* const* d_in, const int* in_sizes, int n_in,
                              void* d_out, int out_size, void* d_ws, size_t ws_size,
                              hipStream_t stream) {
    const float* positions = (const float*)d_in[0];
    const float* cell      = (const float*)d_in[1];
    const float* sigma_tab = (const float*)d_in[2];
    const float* eps_tab   = (const float*)d_in[3];
    const float* shift_tab = (const float*)d_in[4];
    const int*   species   = (const int*)d_in[5];
    const int*   pair_i    = (const int*)d_in[6];
    const int*   pair_j    = (const int*)d_in[7];
    const int*   shifts    = (const int*)d_in[8];
    float* energy = (float*)d_out;

    const int N = out_size;
    const int P = in_sizes[6];

    const int threads = 256;
    const int ablocks = (N + threads - 1) / threads;
    const int pblocks4 = (int)((((long)P + 3) / 4 + threads - 1) / threads);

    // Bucket path sizing.
    const int nb = (N + BUCKET_SIZE - 1) / BUCKET_SIZE;
    long avg = (2L * P) / (nb > 0 ? nb : 1);
    long capl = (avg + avg / 50 + 512 + 1023) & ~1023L;
    const int cap = (int)capl;
    // ws layout: [records nb*cap u32][tab8 N u64][cursor nb i32]
    const size_t rec_bytes  = (size_t)nb * (size_t)cap * 4u;
    const size_t tab_bytes  = (size_t)N * 8u;
    const size_t cur_bytes  = (size_t)nb * 4u;
    const size_t need_bucket = rec_bytes + tab_bytes + cur_bytes;
    const size_t need_pack   = (size_t)N * 16u;

    const bool has_ws = (d_ws != nullptr);
    const bool sane = (nb > 0) && (nb <= 256) && ((long)nb * cap < 2000000000L);
    const bool use_bucket = has_ws && sane && (ws_size >= need_bucket);
    const bool use_pack   = has_ws && !use_bucket && (ws_size >= need_pack);

    if (use_bucket) {
        unsigned int* record_buf = (unsigned int*)d_ws;
        unsigned long long* tab8 = (unsigned long long*)((char*)d_ws + rec_bytes);
        int* cursor = (int*)((char*)d_ws + rec_bytes + tab_bytes);

        lj_zero_kernel<<<ablocks, threads, 0, stream>>>(energy, N);
        lj_pack8_kernel<<<ablocks, threads, 0, stream>>>(
            positions, species, tab8, cursor, nb, cap, N);
        const long nthreads_needed = ((long)P + A_PAIRS - 1) / A_PAIRS;
        const int pblocksA = (int)((nthreads_needed + A_THREADS - 1) / A_THREADS);
        lj_passA_kernel<<<pblocksA, A_THREADS, 0, stream>>>(
            tab8, cell, sigma_tab, eps_tab, shift_tab,
            pair_i, pair_j, shifts, record_buf, cursor, cap, nb, P);
        lj_passB_atomic_kernel<<<nb * SLICES, threads, 0, stream>>>(
            record_buf, cursor, energy, cap, N);
    } else if (use_pack) {
        float4* packed = (float4*)d_ws;
        lj_zero_kernel<<<ablocks, threads, 0, stream>>>(energy, N);
        lj_pack_kernel<<<ablocks, threads, 0, stream>>>(positions, species, packed, N);
        lj_pairs_packed_kernel<<<pblocks4, threads, 0, stream>>>(
            packed, cell, sigma_tab, eps_tab, shift_tab,
            pair_i, pair_j, shifts, energy, P);
    } else {
        lj_zero_kernel<<<ablocks, threads, 0, stream>>>(energy, N);
        lj_pairs_kernel<<<pblocks4, threads, 0, stream>>>(
            positions, cell, sigma_tab, eps_tab, shift_tab, species,
            pair_i, pair_j, shifts, energy, P);
    }
}

// Round 10
// 719.058 us; speedup vs baseline: 1.0300x; 1.0300x over previous
//
#include <hip/hip_runtime.h>

// ---------------------------------------------------------------------------
// LennardJones per-atom energy — bucketed two-pass.
//
// R22: identical resubmit of R21 — round 9 was an infra failure (container
// died twice; same env flake seen in rounds 0/4/5, including on proven
// kernels). R21's occupancy theory has never executed; source kept
// byte-identical for attribution.
//
// R21: occupancy-driven passA. Evidence through R20: wall-minus-passA is a
// back-end-invariant 414-416us (3 different passB structures) -> fixed
// overhead + small passB; passA (324us) is the only attackable term.
// passA is latency-throughput bound on 32M tab8 gathers (745MB FETCH = 425MB
// tab8 L2-thrash re-fetch; 14 waves/CU x ~4 outstanding = ~320us — matches).
// Lever: waves/CU, capped by LDS (44.5KB -> 3 blocks).
//  * A_PAIRS 8 -> 4: 4096 records/block, LDS ~23KB -> 4 blocks x 8 waves
//    = 32 waves/CU (100% cap), 2.3x current. Run length 33 -> 16.7 records
//    (write-segment cost ~+15-20us, gather win ~-140us).
//  * passB: R19's direct-write one-block-per-bucket (245 x 1024); no zero
//    dispatch (R19==R20 proved back-end forms equivalent).
// Predicted: passA occ -> ~85-100%, dur -> ~180-210us; wall -> ~590-630.
// ws-guarded; fallbacks: R7 packed float4, then R1.
// ---------------------------------------------------------------------------

#define BUCKET_SHIFT 11
#define BUCKET_SIZE  2048
#define QSCALE       2048.0f
#define QINV         (1.0f / 2048.0f)

#define A_THREADS 512
#define A_PAIRS   4
#define A_RECORDS (A_THREADS * A_PAIRS * 2)   // 4096

typedef int vint4 __attribute__((ext_vector_type(4)));

__global__ void lj_zero_kernel(float* __restrict__ out, long n) {
    long i = (long)blockIdx.x * blockDim.x + threadIdx.x;
    if (i < n) out[i] = 0.0f;
}

// tab8[a] = x_u16 | y_u16<<16 | z_u16<<32 | species<<48  (coords * 2048)
// Also initializes cursor[b] = b * cap (folded to save a dispatch).
__global__ void lj_pack8_kernel(const float* __restrict__ pos,
                                const int* __restrict__ species,
                                unsigned long long* __restrict__ tab8,
                                int* __restrict__ cursor,
                                int nb, int cap, int n) {
    int i = blockIdx.x * blockDim.x + threadIdx.x;
    if (i < n) {
        unsigned int ux = (unsigned int)(pos[3 * i]     * QSCALE + 0.5f) & 0xFFFFu;
        unsigned int uy = (unsigned int)(pos[3 * i + 1] * QSCALE + 0.5f) & 0xFFFFu;
        unsigned int uz = (unsigned int)(pos[3 * i + 2] * QSCALE + 0.5f) & 0xFFFFu;
        unsigned long long w = (unsigned long long)ux
                             | ((unsigned long long)uy << 16)
                             | ((unsigned long long)uz << 32)
                             | ((unsigned long long)(species[i] & 3) << 48);
        tab8[i] = w;
    }
    if (i < nb) cursor[i] = i * cap;
}

// float4 pack (fallback path)
__global__ void lj_pack_kernel(const float* __restrict__ pos,
                               const int* __restrict__ species,
                               float4* __restrict__ packed, int n) {
    int i = blockIdx.x * blockDim.x + threadIdx.x;
    if (i < n) {
        float4 p;
        p.x = pos[3 * i];
        p.y = pos[3 * i + 1];
        p.z = pos[3 * i + 2];
        p.w = __int_as_float(species[i]);
        packed[i] = p;
    }
}

// Encode: round he's f32 bits to 12 mantissa bits, pack local id in low 11.
__device__ __forceinline__ unsigned int lj_encode(float he) {
    unsigned int u = __float_as_uint(he);
    return (u + 0x400u) & 0xFFFFF800u;
}

__global__ __launch_bounds__(A_THREADS) void lj_passA_kernel(
    const unsigned long long* __restrict__ tab8,
    const float* __restrict__ cell,
    const float* __restrict__ sigma_tab,
    const float* __restrict__ eps_tab,
    const float* __restrict__ shift_tab,
    const int* __restrict__ pair_i,
    const int* __restrict__ pair_j,
    const int* __restrict__ shifts,
    unsigned int* __restrict__ record_buf,
    int* __restrict__ cursor,
    int cap, int nb, int P)
{
    __shared__ float s_sig6[16];
    __shared__ float s_eps4[16];
    __shared__ float s_shift[16];
    __shared__ float s_cell[9];
    __shared__ int hist[256];
    __shared__ int basev[256];   // global (per-bucket) reservation start
    __shared__ int bbase[256];   // block-local exclusive prefix of hist
    __shared__ unsigned int staged[A_RECORDS];       // bucket-sorted records
    __shared__ unsigned char bucketOf[A_RECORDS];    // bucket id per slot
    int t = threadIdx.x;
    if (t < 16) {
        float s = sigma_tab[t];
        float s3 = s * s * s;
        s_sig6[t] = s3 * s3;
        s_eps4[t] = 4.0f * eps_tab[t];
        s_shift[t] = shift_tab[t];
    }
    if (t < 9) s_cell[t] = cell[t];
    if (t < 256) hist[t] = 0;
    __syncthreads();

    float c00 = s_cell[0], c01 = s_cell[1], c02 = s_cell[2];
    float c10 = s_cell[3], c11 = s_cell[4], c12 = s_cell[5];
    float c20 = s_cell[6], c21 = s_cell[7], c22 = s_cell[8];

    long base = (long)(blockIdx.x * (long)A_THREADS + t) * A_PAIRS;

    unsigned int encI[A_PAIRS], encJ[A_PAIRS];  // full records (he | local id)
    int slotij[A_PAIRS];                        // sloti | slotj<<16
    int bkt[A_PAIRS];                           // bi | bj<<8
    int vmask = 0;                              // per-pair validity bits

    if (base + (A_PAIRS - 1) < P) {
        vmask = (1 << A_PAIRS) - 1;
        vint4 pi4 = *(const vint4*)(pair_i + base);
        vint4 pj4 = *(const vint4*)(pair_j + base);
        int pis[A_PAIRS] = {pi4[0], pi4[1], pi4[2], pi4[3]};
        int pjs[A_PAIRS] = {pj4[0], pj4[1], pj4[2], pj4[3]};

        // issue all 8 gathers before any consumption
        unsigned long long gi[A_PAIRS], gj[A_PAIRS];
#pragma unroll
        for (int k = 0; k < A_PAIRS; ++k) {
            gi[k] = tab8[pis[k]];
            gj[k] = tab8[pjs[k]];
        }

        vint4 s0 = *(const vint4*)(shifts + base * 3);
        vint4 s1 = *(const vint4*)(shifts + base * 3 + 4);
        vint4 s2 = *(const vint4*)(shifts + base * 3 + 8);
        int shv[12] = {s0[0], s0[1], s0[2], s0[3],
                       s1[0], s1[1], s1[2], s1[3],
                       s2[0], s2[1], s2[2], s2[3]};

#pragma unroll
        for (int k = 0; k < A_PAIRS; ++k) {
            float fx = (float)shv[3 * k], fy = (float)shv[3 * k + 1], fz = (float)shv[3 * k + 2];
            unsigned long long wi = gi[k], wj = gj[k];
            int xi = (int)(wi & 0xFFFFu), yi = (int)((wi >> 16) & 0xFFFFu), zi = (int)((wi >> 32) & 0xFFFFu);
            int xj = (int)(wj & 0xFFFFu), yj = (int)((wj >> 16) & 0xFFFFu), zj = (int)((wj >> 32) & 0xFFFFu);
            float dlx = (float)(xj - xi) * QINV;
            float dly = (float)(yj - yi) * QINV;
            float dlz = (float)(zj - zi) * QINV;
            float dx = dlx + fx * c00 + fy * c10 + fz * c20;
            float dy = dly + fx * c01 + fy * c11 + fz * c21;
            float dz = dlz + fx * c02 + fy * c12 + fz * c22;
            float r2 = dx * dx + dy * dy + dz * dz;
            float r6 = r2 * r2 * r2;
            int idx = (int)(wi >> 48) * 4 + (int)(wj >> 48);
            float sr6 = s_sig6[idx] / r6;
            float sr12 = sr6 * sr6;
            float he = 0.5f * (s_eps4[idx] * (sr12 - sr6) - s_shift[idx]);
            unsigned int u = lj_encode(he);
            encI[k] = u | (unsigned int)(pis[k] & (BUCKET_SIZE - 1));
            encJ[k] = u | (unsigned int)(pjs[k] & (BUCKET_SIZE - 1));
            bkt[k] = (pis[k] >> BUCKET_SHIFT) | ((pjs[k] >> BUCKET_SHIFT) << 8);
        }
    } else {
#pragma unroll
        for (int k = 0; k < A_PAIRS; ++k) {
            long p = base + k;
            encI[k] = 0; encJ[k] = 0; bkt[k] = 0;
            if (p < P) {
                vmask |= (1 << k);
                int i = pair_i[p], j = pair_j[p];
                float fx = (float)shifts[3 * p], fy = (float)shifts[3 * p + 1], fz = (float)shifts[3 * p + 2];
                unsigned long long wi = tab8[i];
                unsigned long long wj = tab8[j];
                int xi = (int)(wi & 0xFFFFu), yi = (int)((wi >> 16) & 0xFFFFu), zi = (int)((wi >> 32) & 0xFFFFu);
                int xj = (int)(wj & 0xFFFFu), yj = (int)((wj >> 16) & 0xFFFFu), zj = (int)((wj >> 32) & 0xFFFFu);
                float dlx = (float)(xj - xi) * QINV;
                float dly = (float)(yj - yi) * QINV;
                float dlz = (float)(zj - zi) * QINV;
                float dx = dlx + fx * c00 + fy * c10 + fz * c20;
                float dy = dly + fx * c01 + fy * c11 + fz * c21;
                float dz = dlz + fx * c02 + fy * c12 + fz * c22;
                float r2 = dx * dx + dy * dy + dz * dz;
                float r6 = r2 * r2 * r2;
                int idx = (int)(wi >> 48) * 4 + (int)(wj >> 48);
                float sr6 = s_sig6[idx] / r6;
                float sr12 = sr6 * sr6;
                float he = 0.5f * (s_eps4[idx] * (sr12 - sr6) - s_shift[idx]);
                unsigned int u = lj_encode(he);
                encI[k] = u | (unsigned int)(i & (BUCKET_SIZE - 1));
                encJ[k] = u | (unsigned int)(j & (BUCKET_SIZE - 1));
                bkt[k] = (i >> BUCKET_SHIFT) | ((j >> BUCKET_SHIFT) << 8);
            }
        }
    }

    // Histogram phase (LDS atomics) — slot = rank within (block, bucket).
#pragma unroll
    for (int k = 0; k < A_PAIRS; ++k) {
        if (vmask & (1 << k)) {
            int si = atomicAdd(&hist[bkt[k] & 255], 1);
            int sj = atomicAdd(&hist[(bkt[k] >> 8) & 255], 1);
            slotij[k] = si | (sj << 16);
        } else {
            slotij[k] = 0;
        }
    }
    __syncthreads();

    // Wave 0: exclusive scan of hist -> bbase (block-local bucket offsets).
    if (t < 64) {
        int b0 = t * 4;
        int h0 = hist[b0], h1 = hist[b0 + 1], h2 = hist[b0 + 2], h3 = hist[b0 + 3];
        int s = h0 + h1 + h2 + h3;
        int incl = s;
#pragma unroll
        for (int d = 1; d < 64; d <<= 1) {
            int v = __shfl_up(incl, d, 64);
            if (t >= d) incl += v;
        }
        int excl = incl - s;
        bbase[b0]     = excl;
        bbase[b0 + 1] = excl + h0;
        bbase[b0 + 2] = excl + h0 + h1;
        bbase[b0 + 3] = excl + h0 + h1 + h2;
    }
    // Reserve per-bucket space: ONE global atomic per touched bucket per block.
    if (t < nb) {
        int h = hist[t];
        basev[t] = (h > 0) ? atomicAdd(&cursor[t], h) : 0;
    }
    __syncthreads();

    // Stage records into LDS, bucket-sorted.
#pragma unroll
    for (int k = 0; k < A_PAIRS; ++k) {
        if (vmask & (1 << k)) {
            int bi = bkt[k] & 255;
            int li = bbase[bi] + (slotij[k] & 0xFFFF);
            staged[li] = encI[k];
            bucketOf[li] = (unsigned char)bi;
            int bj = (bkt[k] >> 8) & 255;
            int lj = bbase[bj] + (slotij[k] >> 16);
            staged[lj] = encJ[k];
            bucketOf[lj] = (unsigned char)bj;
        }
    }
    __syncthreads();

    // Coalesced flush: sorted LDS order == contiguous global order per run.
    int total = bbase[255] + hist[255];
    for (int idx = t; idx < total; idx += A_THREADS) {
        int b = (int)bucketOf[idx];
        int g = basev[b] + (idx - bbase[b]);
        if (g < (b + 1) * cap) record_buf[g] = staged[idx];
    }
}

// R19 passB: ONE 1024-thread block per bucket (exclusive ownership).
// Accumulate the bucket's records into LDS and write energy directly.
__global__ __launch_bounds__(1024) void lj_passB1_kernel(
    const unsigned int* __restrict__ record_buf,
    const int* __restrict__ cursor,
    float* __restrict__ energy,
    int cap, int N)
{
    __shared__ float e[BUCKET_SIZE];
    int b = blockIdx.x;
    int t = threadIdx.x;
    e[t] = 0.0f;
    e[t + 1024] = 0.0f;
    __syncthreads();

    int begin = b * cap;
    int count = cursor[b] - begin;
    if (count > cap) count = cap;

    int full = count >> 3;  // complete groups of 8 records
    for (int g = t; g < full; g += 1024) {
        const unsigned int* rp = record_buf + begin + g * 8;
        vint4 a = *(const vint4*)(rp);
        vint4 c = *(const vint4*)(rp + 4);
        unsigned int w0 = (unsigned int)a[0], w1 = (unsigned int)a[1];
        unsigned int w2 = (unsigned int)a[2], w3 = (unsigned int)a[3];
        unsigned int w4 = (unsigned int)c[0], w5 = (unsigned int)c[1];
        unsigned int w6 = (unsigned int)c[2], w7 = (unsigned int)c[3];
        atomicAdd(&e[w0 & 2047u], __uint_as_float(w0 & 0xFFFFF800u));
        atomicAdd(&e[w1 & 2047u], __uint_as_float(w1 & 0xFFFFF800u));
        atomicAdd(&e[w2 & 2047u], __uint_as_float(w2 & 0xFFFFF800u));
        atomicAdd(&e[w3 & 2047u], __uint_as_float(w3 & 0xFFFFF800u));
        atomicAdd(&e[w4 & 2047u], __uint_as_float(w4 & 0xFFFFF800u));
        atomicAdd(&e[w5 & 2047u], __uint_as_float(w5 & 0xFFFFF800u));
        atomicAdd(&e[w6 & 2047u], __uint_as_float(w6 & 0xFFFFF800u));
        atomicAdd(&e[w7 & 2047u], __uint_as_float(w7 & 0xFFFFF800u));
    }
    // tail records
    for (int r = (full << 3) + t; r < count; r += 1024) {
        unsigned int w = record_buf[begin + r];
        atomicAdd(&e[w & 2047u], __uint_as_float(w & 0xFFFFF800u));
    }
    __syncthreads();

    long i0 = (long)b * BUCKET_SIZE + t;
    if (i0 < N) energy[i0] = e[t];
    if (i0 + 1024 < N) energy[i0 + 1024] = e[t + 1024];
}

// ------------------- R7 packed fallback (proven, 1561 us) -------------------
__device__ __forceinline__ void lj_one_pair_packed(
    int i, int j, float fx, float fy, float fz,
    const float4* __restrict__ packed,
    const float* s_sig6, const float* s_eps4, const float* s_shift,
    float c00, float c01, float c02,
    float c10, float c11, float c12,
    float c20, float c21, float c22,
    float* __restrict__ energy)
{
    float4 gi = packed[i];
    float4 gj = packed[j];
    float dx = gj.x - gi.x + fx * c00 + fy * c10 + fz * c20;
    float dy = gj.y - gi.y + fx * c01 + fy * c11 + fz * c21;
    float dz = gj.z - gi.z + fx * c02 + fy * c12 + fz * c22;
    float r2 = dx * dx + dy * dy + dz * dz;
    float r6 = r2 * r2 * r2;
    int idx = __float_as_int(gi.w) * 4 + __float_as_int(gj.w);
    float sr6 = s_sig6[idx] / r6;
    float sr12 = sr6 * sr6;
    float he = 0.5f * (s_eps4[idx] * (sr12 - sr6) - s_shift[idx]);
    atomicAdd(energy + i, he);
    atomicAdd(energy + j, he);
}

__global__ __launch_bounds__(256) void lj_pairs_packed_kernel(
    const float4* __restrict__ packed,
    const float* __restrict__ cell,
    const float* __restrict__ sigma_tab,
    const float* __restrict__ eps_tab,
    const float* __restrict__ shift_tab,
    const int* __restrict__ pair_i,
    const int* __restrict__ pair_j,
    const int* __restrict__ shifts,
    float* __restrict__ energy,
    int P)
{
    __shared__ float s_sig6[16];
    __shared__ float s_eps4[16];
    __shared__ float s_shift[16];
    __shared__ float s_cell[9];
    int t = threadIdx.x;
    if (t < 16) {
        float s = sigma_tab[t];
        float s3 = s * s * s;
        s_sig6[t] = s3 * s3;
        s_eps4[t] = 4.0f * eps_tab[t];
        s_shift[t] = shift_tab[t];
    }
    if (t < 9) s_cell[t] = cell[t];
    __syncthreads();

    float c00 = s_cell[0], c01 = s_cell[1], c02 = s_cell[2];
    float c10 = s_cell[3], c11 = s_cell[4], c12 = s_cell[5];
    float c20 = s_cell[6], c21 = s_cell[7], c22 = s_cell[8];

    long base = (long)(blockIdx.x * (long)blockDim.x + t) * 4;
    if (base + 3 < P) {
        int4 pi4 = *(const int4*)(pair_i + base);
        int4 pj4 = *(const int4*)(pair_j + base);
        int4 sA = *(const int4*)(shifts + base * 3);
        int4 sB = *(const int4*)(shifts + base * 3 + 4);
        int4 sC = *(const int4*)(shifts + base * 3 + 8);
        int pis[4] = {pi4.x, pi4.y, pi4.z, pi4.w};
        int pjs[4] = {pj4.x, pj4.y, pj4.z, pj4.w};
        int shv[12] = {sA.x, sA.y, sA.z, sA.w, sB.x, sB.y, sB.z, sB.w,
                       sC.x, sC.y, sC.z, sC.w};
#pragma unroll
        for (int k = 0; k < 4; ++k) {
            lj_one_pair_packed(pis[k], pjs[k],
                        (float)shv[3 * k], (float)shv[3 * k + 1], (float)shv[3 * k + 2],
                        packed, s_sig6, s_eps4, s_shift,
                        c00, c01, c02, c10, c11, c12, c20, c21, c22, energy);
        }
    } else {
        for (long p = base; p < P; ++p) {
            lj_one_pair_packed(pair_i[p], pair_j[p],
                        (float)shifts[3 * p], (float)shifts[3 * p + 1], (float)shifts[3 * p + 2],
                        packed, s_sig6, s_eps4, s_shift,
                        c00, c01, c02, c10, c11, c12, c20, c21, c22, energy);
        }
    }
}

// --------------------- R1 fallback (no workspace at all) --------------------
__device__ __forceinline__ void lj_one_pair(
    int i, int j, float fx, float fy, float fz,
    const float* __restrict__ pos,
    const int* __restrict__ species,
    const float* s_sig6, const float* s_eps4, const float* s_shift,
    float c00, float c01, float c02,
    float c10, float c11, float c12,
    float c20, float c21, float c22,
    float* __restrict__ energy)
{
    float dx = pos[3 * j]     - pos[3 * i]     + fx * c00 + fy * c10 + fz * c20;
    float dy = pos[3 * j + 1] - pos[3 * i + 1] + fx * c01 + fy * c11 + fz * c21;
    float dz = pos[3 * j + 2] - pos[3 * i + 2] + fx * c02 + fy * c12 + fz * c22;
    float r2 = dx * dx + dy * dy + dz * dz;
    float r6 = r2 * r2 * r2;
    int idx = species[i] * 4 + species[j];
    float sr6 = s_sig6[idx] / r6;
    float sr12 = sr6 * sr6;
    float he = 0.5f * (s_eps4[idx] * (sr12 - sr6) - s_shift[idx]);
    atomicAdd(energy + i, he);
    atomicAdd(energy + j, he);
}

__global__ __launch_bounds__(256) void lj_pairs_kernel(
    const float* __restrict__ pos,
    const float* __restrict__ cell,
    const float* __restrict__ sigma_tab,
    const float* __restrict__ eps_tab,
    const float* __restrict__ shift_tab,
    const int* __restrict__ species,
    const int* __restrict__ pair_i,
    const int* __restrict__ pair_j,
    const int* __restrict__ shifts,
    float* __restrict__ energy,
    int P)
{
    __shared__ float s_sig6[16];
    __shared__ float s_eps4[16];
    __shared__ float s_shift[16];
    __shared__ float s_cell[9];
    int t = threadIdx.x;
    if (t < 16) {
        float s = sigma_tab[t];
        float s3 = s * s * s;
        s_sig6[t] = s3 * s3;
        s_eps4[t] = 4.0f * eps_tab[t];
        s_shift[t] = shift_tab[t];
    }
    if (t < 9) s_cell[t] = cell[t];
    __syncthreads();

    float c00 = s_cell[0], c01 = s_cell[1], c02 = s_cell[2];
    float c10 = s_cell[3], c11 = s_cell[4], c12 = s_cell[5];
    float c20 = s_cell[6], c21 = s_cell[7], c22 = s_cell[8];

    long base = (long)(blockIdx.x * (long)blockDim.x + t) * 4;
    if (base + 3 < P) {
        int4 pi4 = *(const int4*)(pair_i + base);
        int4 pj4 = *(const int4*)(pair_j + base);
        int4 sA = *(const int4*)(shifts + base * 3);
        int4 sB = *(const int4*)(shifts + base * 3 + 4);
        int4 sC = *(const int4*)(shifts + base * 3 + 8);
        int pis[4] = {pi4.x, pi4.y, pi4.z, pi4.w};
        int pjs[4] = {pj4.x, pj4.y, pj4.z, pj4.w};
        int shv[12] = {sA.x, sA.y, sA.z, sA.w, sB.x, sB.y, sB.z, sB.w,
                       sC.x, sC.y, sC.z, sC.w};
#pragma unroll
        for (int k = 0; k < 4; ++k) {
            lj_one_pair(pis[k], pjs[k],
                        (float)shv[3 * k], (float)shv[3 * k + 1], (float)shv[3 * k + 2],
                        pos, species, s_sig6, s_eps4, s_shift,
                        c00, c01, c02, c10, c11, c12, c20, c21, c22, energy);
        }
    } else {
        for (long p = base; p < P; ++p) {
            lj_one_pair(pair_i[p], pair_j[p],
                        (float)shifts[3 * p], (float)shifts[3 * p + 1], (float)shifts[3 * p + 2],
                        pos, species, s_sig6, s_eps4, s_shift,
                        c00, c01, c02, c10, c11, c12, c20, c21, c22, energy);
        }
    }
}

extern "C" void kernel_launch(void* const* d_in, const int* in_sizes, int n_in,
                              void* d_out, int out_size, void* d_ws, size_t ws_size,
                              hipStream_t stream) {
    const float* positions = (const float*)d_in[0];
    const float* cell      = (const float*)d_in[1];
    const float* sigma_tab = (const float*)d_in[2];
    const float* eps_tab   = (const float*)d_in[3];
    const float* shift_tab = (const float*)d_in[4];
    const int*   species   = (const int*)d_in[5];
    const int*   pair_i    = (const int*)d_in[6];
    const int*   pair_j    = (const int*)d_in[7];
    const int*   shifts    = (const int*)d_in[8];
    float* energy = (float*)d_out;

    const int N = out_size;
    const int P = in_sizes[6];

    const int threads = 256;
    const int ablocks = (N + threads - 1) / threads;
    const int pblocks4 = (int)((((long)P + 3) / 4 + threads - 1) / threads);

    // Bucket path sizing.
    const int nb = (N + BUCKET_SIZE - 1) / BUCKET_SIZE;
    long avg = (2L * P) / (nb > 0 ? nb : 1);
    long capl = (avg + avg / 50 + 512 + 1023) & ~1023L;
    const int cap = (int)capl;
    // ws layout: [records nb*cap u32][tab8 N u64][cursor nb i32]
    const size_t rec_bytes  = (size_t)nb * (size_t)cap * 4u;
    const size_t tab_bytes  = (size_t)N * 8u;
    const size_t cur_bytes  = (size_t)nb * 4u;
    const size_t need_bucket = rec_bytes + tab_bytes + cur_bytes;
    const size_t need_pack   = (size_t)N * 16u;

    const bool has_ws = (d_ws != nullptr);
    const bool sane = (nb > 0) && (nb <= 256) && ((long)nb * cap < 2000000000L);
    const bool use_bucket = has_ws && sane && (ws_size >= need_bucket);
    const bool use_pack   = has_ws && !use_bucket && (ws_size >= need_pack);

    if (use_bucket) {
        unsigned int* record_buf = (unsigned int*)d_ws;
        unsigned long long* tab8 = (unsigned long long*)((char*)d_ws + rec_bytes);
        int* cursor = (int*)((char*)d_ws + rec_bytes + tab_bytes);

        lj_pack8_kernel<<<ablocks, threads, 0, stream>>>(
            positions, species, tab8, cursor, nb, cap, N);
        const long nthreads_needed = ((long)P + A_PAIRS - 1) / A_PAIRS;
        const int pblocksA = (int)((nthreads_needed + A_THREADS - 1) / A_THREADS);
        lj_passA_kernel<<<pblocksA, A_THREADS, 0, stream>>>(
            tab8, cell, sigma_tab, eps_tab, shift_tab,
            pair_i, pair_j, shifts, record_buf, cursor, cap, nb, P);
        lj_passB1_kernel<<<nb, 1024, 0, stream>>>(record_buf, cursor, energy, cap, N);
    } else if (use_pack) {
        float4* packed = (float4*)d_ws;
        lj_zero_kernel<<<ablocks, threads, 0, stream>>>(energy, N);
        lj_pack_kernel<<<ablocks, threads, 0, stream>>>(positions, species, packed, N);
        lj_pairs_packed_kernel<<<pblocks4, threads, 0, stream>>>(
            packed, cell, sigma_tab, eps_tab, shift_tab,
            pair_i, pair_j, shifts, energy, P);
    } else {
        lj_zero_kernel<<<ablocks, threads, 0, stream>>>(energy, N);
        lj_pairs_kernel<<<pblocks4, threads, 0, stream>>>(
            positions, cell, sigma_tab, eps_tab, shift_tab, species,
            pair_i, pair_j, shifts, energy, P);
    }
}